// Round 3
// baseline (676.599 us; speedup 1.0000x reference)
//
#include <hip/hip_runtime.h>
#include <cstdint>

typedef _Float16 f16;
typedef __attribute__((ext_vector_type(8))) _Float16 f16x8;
typedef __attribute__((ext_vector_type(4))) _Float16 f16x4;
typedef __attribute__((ext_vector_type(4))) float f32x4;

typedef __attribute__((address_space(1))) void gvoid_t;
typedef __attribute__((address_space(3))) void lvoid_t;

// async global->LDS, 16B per lane. LDS dest wave-uniform base; HW adds lane*16.
__device__ __forceinline__ void async_copy16(void* lds, const void* g) {
  __builtin_amdgcn_global_load_lds((gvoid_t*)(uintptr_t)g, (lvoid_t*)lds, 16, 0, 0);
}

// Builtin barrier: a real scheduling boundary (rule #18: asm barriers let the
// scheduler hoist register-only MFMA past them, dissolving the phase schedule).
#define BARRIER()   __builtin_amdgcn_s_barrier()
#define SCHEDBAR()  __builtin_amdgcn_sched_barrier(0)
#define VMCNT4()    do { asm volatile("s_waitcnt vmcnt(4)"); SCHEDBAR(); } while (0)
#define VMCNT0()    do { asm volatile("s_waitcnt vmcnt(0)"); SCHEDBAR(); } while (0)

// 256x256 tile, BK=32, 8 waves (2M x 4N), 4-deep LDS ring, counted vmcnt.
// C[z][m][n] = scale * sum_k A[z][m][k]*B[z][n][k] + bias[n]
template<int OUT_F16>
__global__ __launch_bounds__(512, 2)
void gemm256(const f16* __restrict__ A, int lda, long sA,
             const f16* __restrict__ B, int ldb, long sB,
             void* __restrict__ Cv, int ldc, long sC,
             const float* __restrict__ bias, float scale, int K)
{
  __shared__ f16 SA[4][256 * 32];   // 4 x 16 KB
  __shared__ f16 SB[4][256 * 32];   // 4 x 16 KB  (total 128 KB)

  const int tid  = threadIdx.x;
  const int lane = tid & 63;
  const int wave = tid >> 6;        // 0..7
  const int wr = wave >> 2;         // 0..1 : M half (128 rows)
  const int wc = wave & 3;          // 0..3 : N quarter (64 cols)
  const int l15 = lane & 15, lk = lane >> 4;

  const long brow = (long)blockIdx.y * 256;
  const long bcol = (long)blockIdx.x * 256;
  const int z = blockIdx.z;
  const f16* Ab = A + (long)z * sA;
  const f16* Bb = B + (long)z * sB;

  // staging geometry: thread tid owns LDS slot (row = tid>>2, col8 = tid&3);
  // global source col pre-swizzled so LDS[row][c] holds global col (c ^ ((row>>1)&3)).
  const int srow  = tid >> 2;                       // 0..127
  const int scol8 = (tid & 3) ^ ((tid >> 3) & 3);   // pre-swizzled col block
  const int sdst  = wave * 512;                     // wave-uniform elem offset in half

#define STAGE_A(sb, tt) {                                                        \
    async_copy16(&SA[sb][sdst],                                                  \
                 Ab + (brow + srow) * (long)lda + (long)(tt) * 32 + scol8 * 8);  \
    async_copy16(&SA[sb][4096 + sdst],                                           \
                 Ab + (brow + 128 + srow) * (long)lda + (long)(tt) * 32 + scol8 * 8); }
#define STAGE_B(sb, tt) {                                                        \
    async_copy16(&SB[sb][sdst],                                                  \
                 Bb + (bcol + srow) * (long)ldb + (long)(tt) * 32 + scol8 * 8);  \
    async_copy16(&SB[sb][4096 + sdst],                                           \
                 Bb + (bcol + 128 + srow) * (long)ldb + (long)(tt) * 32 + scol8 * 8); }

// swizzled ds_read of one 16-row fragment (f16x8 per lane)
#define RD_A(dst, buf, mm) { const int ra = wr * 128 + (mm) * 16 + l15;          \
    dst = *reinterpret_cast<const f16x8*>(&SA[buf][ra * 32 + ((lk ^ ((ra >> 1) & 3)) * 8)]); }
#define RD_B(dst, buf, nn) { const int rb = wc * 64 + (nn) * 16 + l15;           \
    dst = *reinterpret_cast<const f16x8*>(&SB[buf][rb * 32 + ((lk ^ ((rb >> 1) & 3)) * 8)]); }

  f32x4 acc[8][4] = {};
  const int NT = K >> 5;

  // prologue: stage tiles 0 and 1 (8 loads); wait tile 0 (leave tile 1 in flight)
  STAGE_A(0, 0); STAGE_B(0, 0);
  STAGE_A(1, 1); STAGE_B(1, 1);
  VMCNT4();
  BARRIER();

  for (int t = 0; t < NT; ++t) {
    const int buf = t & 3;
    const int sb  = (t + 2) & 3;
    const bool st = (t + 2) < NT;
    f16x8 af[4], bf[4];

    // ---- phase 0: stage A(t+2) | read A(m0..3)+B | 16 MFMA ----
    if (st) STAGE_A(sb, t + 2);
    RD_A(af[0], buf, 0); RD_A(af[1], buf, 1); RD_A(af[2], buf, 2); RD_A(af[3], buf, 3);
    RD_B(bf[0], buf, 0); RD_B(bf[1], buf, 1); RD_B(bf[2], buf, 2); RD_B(bf[3], buf, 3);
    BARRIER();
    __builtin_amdgcn_s_setprio(1);
#pragma unroll
    for (int m = 0; m < 4; ++m)
#pragma unroll
      for (int n = 0; n < 4; ++n)
        acc[m][n] = __builtin_amdgcn_mfma_f32_16x16x32_f16(af[m], bf[n], acc[m][n], 0, 0, 0);
    __builtin_amdgcn_s_setprio(0);
    BARRIER();

    // ---- phase 1: stage B(t+2) | read A(m4..7) | 16 MFMA ----
    if (st) STAGE_B(sb, t + 2);
    RD_A(af[0], buf, 4); RD_A(af[1], buf, 5); RD_A(af[2], buf, 6); RD_A(af[3], buf, 7);
    BARRIER();
    __builtin_amdgcn_s_setprio(1);
#pragma unroll
    for (int m = 0; m < 4; ++m)
#pragma unroll
      for (int n = 0; n < 4; ++n)
        acc[m + 4][n] = __builtin_amdgcn_mfma_f32_16x16x32_f16(af[m], bf[n], acc[m + 4][n], 0, 0, 0);
    __builtin_amdgcn_s_setprio(0);
    // end of tile: ensure tile t+1 landed; leave tile t+2 (4 loads) in flight
    if (st) { VMCNT4(); } else { VMCNT0(); }
    BARRIER();
  }

  // epilogue: C/D layout col = lane&15, row = (lane>>4)*4 + j
#pragma unroll
  for (int m = 0; m < 8; ++m) {
#pragma unroll
    for (int n = 0; n < 4; ++n) {
      const long col = bcol + wc * 64 + n * 16 + l15;
      const float bv = bias ? bias[col] : 0.0f;
#pragma unroll
      for (int j = 0; j < 4; ++j) {
        const long row = brow + wr * 128 + m * 16 + lk * 4 + j;
        const float v = acc[m][n][j] * scale + bv;
        if (OUT_F16)
          ((f16*)Cv)[(long)z * sC + row * ldc + col] = (f16)v;
        else
          ((float*)Cv)[(long)z * sC + row * ldc + col] = v;
      }
    }
  }
#undef STAGE_A
#undef STAGE_B
#undef RD_A
#undef RD_B
}

__global__ void cast_f32_f16(const float* __restrict__ in, f16* __restrict__ out, long n) {
  long i = ((long)blockIdx.x * blockDim.x + threadIdx.x) * 4;
  const long stride = (long)gridDim.x * blockDim.x * 4;
  for (; i < n; i += stride) {
    const float4 v = *reinterpret_cast<const float4*>(in + i);
    f16x4 h;
    h.x = (f16)v.x; h.y = (f16)v.y; h.z = (f16)v.z; h.w = (f16)v.w;
    *reinterpret_cast<f16x4*>(out + i) = h;
  }
}

// vt[b][h][s] = qkv[b*2048+s][4096+h]   (extract V and transpose, per batch)
__global__ __launch_bounds__(256)
void transpose_v(const f16* __restrict__ qkv, f16* __restrict__ vt) {
  __shared__ f16 t[32][33];
  const int b = blockIdx.z;
  const int s0 = blockIdx.y * 32, h0 = blockIdx.x * 32;
  const int tx = threadIdx.x, ty = threadIdx.y;  // 32 x 8
  const f16* src = qkv + (long)b * 2048 * 6144 + 4096;
  f16* dst = vt + (long)b * 2048 * 2048;
#pragma unroll
  for (int i = 0; i < 4; ++i)
    t[ty + i * 8][tx] = src[(long)(s0 + ty + i * 8) * 6144 + h0 + tx];
  __syncthreads();
#pragma unroll
  for (int i = 0; i < 4; ++i)
    dst[(long)(h0 + ty + i * 8) * 2048 + s0 + tx] = t[tx][ty + i * 8];
}

// one block per row of 2048 f32 scores; writes f16 probs in-place (row stride 4096 f16)
__global__ __launch_bounds__(256)
void softmax_rows(float* __restrict__ scores) {
  const long row = blockIdx.x;
  float* s = scores + row * 2048;
  const int tid = threadIdx.x;
  const int lane = tid & 63;
  const int wave = tid >> 6;

  const float4 a = *reinterpret_cast<const float4*>(s + tid * 8);
  const float4 b = *reinterpret_cast<const float4*>(s + tid * 8 + 4);
  float v[8] = {a.x, a.y, a.z, a.w, b.x, b.y, b.z, b.w};

  float mx = v[0];
#pragma unroll
  for (int j = 1; j < 8; ++j) mx = fmaxf(mx, v[j]);
#pragma unroll
  for (int off = 32; off >= 1; off >>= 1) mx = fmaxf(mx, __shfl_xor(mx, off));
  __shared__ float red[4];
  if (lane == 0) red[wave] = mx;
  __syncthreads();
  mx = fmaxf(fmaxf(red[0], red[1]), fmaxf(red[2], red[3]));

  float sum = 0.f;
#pragma unroll
  for (int j = 0; j < 8; ++j) { v[j] = __expf(v[j] - mx); sum += v[j]; }
#pragma unroll
  for (int off = 32; off >= 1; off >>= 1) sum += __shfl_xor(sum, off);
  __shared__ float red2[4];
  if (lane == 0) red2[wave] = sum;
  __syncthreads();
  const float inv = 1.0f / (red2[0] + red2[1] + red2[2] + red2[3]);

  f16* p = reinterpret_cast<f16*>(scores) + row * 4096 + tid * 8;
  f16x8 h;
#pragma unroll
  for (int j = 0; j < 8; ++j) h[j] = (f16)(v[j] * inv);
  *reinterpret_cast<f16x8*>(p) = h;
}

extern "C" void kernel_launch(void* const* d_in, const int* in_sizes, int n_in,
                              void* d_out, int out_size, void* d_ws, size_t ws_size,
                              hipStream_t stream) {
  const float* x     = (const float*)d_in[0];  // [4,2048,2048]
  const float* w_qkv = (const float*)d_in[1];  // [6144,2048]
  const float* b_qkv = (const float*)d_in[2];  // [6144]
  const float* w_out = (const float*)d_in[3];  // [2048,2048]
  const float* b_out = (const float*)d_in[4];  // [2048]
  float* out = (float*)d_out;                  // [4,2048,2048] f32

  char* ws = (char*)d_ws;
  f16*   Xh    = (f16*)(ws + 0);           //  33.5 MB  [8192][2048]
  f16*   Wqkvh = (f16*)(ws + 33554432L);   //  25.2 MB  [6144][2048]
  f16*   Wouth = (f16*)(ws + 58720256L);   //   8.4 MB  [2048][2048]
  f16*   QKV   = (f16*)(ws + 67108864L);   // 100.7 MB  [8192][6144]
  float* SC    = (float*)(ws + 167772160L);//  67.1 MB  [4][2048][2048] f32 (probs f16 in-place)
  f16*   VT    = (f16*)(ws + 234881024L);  //  33.5 MB  [4][2048][2048]
  f16*   CTX   = Xh;                       // reuse X region after gemm1

  const float inv_sqrt_h = 0.022097086912079608f;  // 1/sqrt(2048)

  cast_f32_f16<<<2048, 256, 0, stream>>>(x,     Xh,    16777216L);
  cast_f32_f16<<<2048, 256, 0, stream>>>(w_qkv, Wqkvh, 12582912L);
  cast_f32_f16<<<1024, 256, 0, stream>>>(w_out, Wouth, 4194304L);

  // qkv = x @ w_qkv^T + b_qkv   [8192 x 6144]
  gemm256<1><<<dim3(24, 32, 1), 512, 0, stream>>>(
      Xh, 2048, 0, Wqkvh, 2048, 0, QKV, 6144, 0, b_qkv, 1.0f, 2048);

  // scores = Q @ K^T / sqrt(H)  per batch  [2048 x 2048] f32
  gemm256<0><<<dim3(8, 8, 4), 512, 0, stream>>>(
      QKV, 6144, 2048L * 6144, QKV + 2048, 6144, 2048L * 6144,
      SC, 2048, 2048L * 2048, nullptr, inv_sqrt_h, 2048);

  transpose_v<<<dim3(64, 64, 4), dim3(32, 8), 0, stream>>>(QKV, VT);

  softmax_rows<<<8192, 256, 0, stream>>>(SC);

  // context = P @ V  per batch (probs f16 in-place in SC, row stride 4096)
  gemm256<1><<<dim3(8, 8, 4), 512, 0, stream>>>(
      (const f16*)SC, 4096, 2048L * 4096, VT, 2048, 2048L * 2048,
      CTX, 2048, 2048L * 2048, nullptr, 1.0f, 2048);

  // out = context @ w_out^T + b_out   [8192 x 2048] f32
  gemm256<0><<<dim3(8, 32, 1), 512, 0, stream>>>(
      CTX, 2048, 0, Wouth, 2048, 0, out, 2048, 0, b_out, 1.0f, 2048);
}

// Round 4
// 530.683 us; speedup vs baseline: 1.2750x; 1.2750x over previous
//
#include <hip/hip_runtime.h>
#include <cstdint>

typedef _Float16 f16;
typedef __attribute__((ext_vector_type(8))) _Float16 f16x8;
typedef __attribute__((ext_vector_type(4))) _Float16 f16x4;
typedef __attribute__((ext_vector_type(4))) float f32x4;

typedef __attribute__((address_space(1))) void gvoid_t;
typedef __attribute__((address_space(3))) void lvoid_t;

// async global->LDS, 16B per lane. LDS dest wave-uniform base; HW adds lane*16.
__device__ __forceinline__ void async_copy16(void* lds, const void* g) {
  __builtin_amdgcn_global_load_lds((gvoid_t*)(uintptr_t)g, (lvoid_t*)lds, 16, 0, 0);
}

#define BARRIER()   __builtin_amdgcn_s_barrier()
#define SCHEDBAR()  __builtin_amdgcn_sched_barrier(0)
#define VMCNT4()    do { asm volatile("s_waitcnt vmcnt(4)"); SCHEDBAR(); } while (0)
#define VMCNT0()    do { asm volatile("s_waitcnt vmcnt(0)"); SCHEDBAR(); } while (0)

struct TileCtx {
  const f16* Ab; const f16* Bb;
  long brow, bcol; int lda, ldb;
  int srow, scol8, sdst;           // staging geometry
  int wr, wc, l15, lk;             // wave/fragment coords
};

// stage one 256x32 half-tile pair half (2 x global_load_lds of 8KB)
__device__ __forceinline__ void stage_half(f16* BUF, const f16* P, long r0, int ld,
                                           int tt, const TileCtx& c) {
  async_copy16(BUF + c.sdst,        P + (r0 + c.srow)       * (long)ld + (long)tt * 32 + c.scol8 * 8);
  async_copy16(BUF + 4096 + c.sdst, P + (r0 + 128 + c.srow) * (long)ld + (long)tt * 32 + c.scol8 * 8);
}

// swizzled ds_read of one 16-row fragment (f16x8 per lane)
__device__ __forceinline__ f16x8 rd_frag(const f16* BUF, int rbase, const TileCtx& c) {
  const int r = rbase + c.l15;
  return *reinterpret_cast<const f16x8*>(&BUF[r * 32 + ((c.lk ^ ((r >> 1) & 3)) * 8)]);
}

// One K-tile (BK=32): read CA/CB (named distinct LDS objects), stage NA/NB for
// tile tc+2. Distinct __shared__ arrays => backend alias analysis does NOT force
// vmcnt(0) before the ds_reads; only our counted vmcnt orders cross-tile.
__device__ __forceinline__ void tile_step(const f16* CA, const f16* CB,
                                          f16* NA, f16* NB,
                                          int tc, int NT, const TileCtx& c,
                                          f32x4 (&acc)[8][4]) {
  const bool st = (tc + 2) < NT;
  f16x8 af[4], bf[4];

  // ---- phase 0: stage A(t+2) | read A(m0..3) + B | 16 MFMA ----
  if (st) stage_half(NA, c.Ab, c.brow, c.lda, tc + 2, c);
  af[0] = rd_frag(CA, c.wr * 128 + 0,  c);
  af[1] = rd_frag(CA, c.wr * 128 + 16, c);
  af[2] = rd_frag(CA, c.wr * 128 + 32, c);
  af[3] = rd_frag(CA, c.wr * 128 + 48, c);
  bf[0] = rd_frag(CB, c.wc * 64 + 0,   c);
  bf[1] = rd_frag(CB, c.wc * 64 + 16,  c);
  bf[2] = rd_frag(CB, c.wc * 64 + 32,  c);
  bf[3] = rd_frag(CB, c.wc * 64 + 48,  c);
  BARRIER();
  __builtin_amdgcn_s_setprio(1);
#pragma unroll
  for (int m = 0; m < 4; ++m)
#pragma unroll
    for (int n = 0; n < 4; ++n)
      acc[m][n] = __builtin_amdgcn_mfma_f32_16x16x32_f16(af[m], bf[n], acc[m][n], 0, 0, 0);
  __builtin_amdgcn_s_setprio(0);
  BARRIER();

  // ---- phase 1: stage B(t+2) | read A(m4..7) | 16 MFMA ----
  if (st) stage_half(NB, c.Bb, c.bcol, c.ldb, tc + 2, c);
  af[0] = rd_frag(CA, c.wr * 128 + 64,  c);
  af[1] = rd_frag(CA, c.wr * 128 + 80,  c);
  af[2] = rd_frag(CA, c.wr * 128 + 96,  c);
  af[3] = rd_frag(CA, c.wr * 128 + 112, c);
  BARRIER();
  __builtin_amdgcn_s_setprio(1);
#pragma unroll
  for (int m = 0; m < 4; ++m)
#pragma unroll
    for (int n = 0; n < 4; ++n)
      acc[m + 4][n] = __builtin_amdgcn_mfma_f32_16x16x32_f16(af[m], bf[n], acc[m + 4][n], 0, 0, 0);
  __builtin_amdgcn_s_setprio(0);
  // tile t+1's 4 loads are the oldest outstanding: wait them, keep t+2's in flight
  if (st) { VMCNT4(); } else { VMCNT0(); }
  BARRIER();
}

// 256x256 tile, BK=32, 8 waves (2M x 4N), 4-deep ring of NAMED LDS buffers.
// C[z][m][n] = scale * sum_k A[z][m][k]*B[z][n][k] + bias[n].  K % 128 == 0.
template<int OUT_F16>
__global__ __launch_bounds__(512, 2)
void gemm256(const f16* __restrict__ A, int lda, long sA,
             const f16* __restrict__ B, int ldb, long sB,
             void* __restrict__ Cv, int ldc, long sC,
             const float* __restrict__ bias, float scale, int K)
{
  __shared__ f16 SA0[8192]; __shared__ f16 SA1[8192];
  __shared__ f16 SA2[8192]; __shared__ f16 SA3[8192];
  __shared__ f16 SB0[8192]; __shared__ f16 SB1[8192];
  __shared__ f16 SB2[8192]; __shared__ f16 SB3[8192];

  const int tid  = threadIdx.x;
  const int lane = tid & 63;
  const int wave = tid >> 6;        // 0..7
  const int z = blockIdx.z;

  TileCtx c;
  c.Ab = A + (long)z * sA;
  c.Bb = B + (long)z * sB;
  c.brow = (long)blockIdx.y * 256;
  c.bcol = (long)blockIdx.x * 256;
  c.lda = lda; c.ldb = ldb;
  c.srow  = tid >> 2;                      // 0..127
  c.scol8 = (tid & 3) ^ ((tid >> 3) & 3);  // pre-swizzled col block (pairs with rd_frag XOR)
  c.sdst  = wave * 512;                    // wave-uniform elem offset within half
  c.wr = wave >> 2;                        // M half (128 rows)
  c.wc = wave & 3;                         // N quarter (64 cols)
  c.l15 = lane & 15; c.lk = lane >> 4;

  f32x4 acc[8][4] = {};
  const int NT = K >> 5;                   // 64 for K=2048

  // prologue: tile0 then tile1 (issue order matters for counted vmcnt)
  stage_half(SA0, c.Ab, c.brow, c.lda, 0, c);
  stage_half(SB0, c.Bb, c.bcol, c.ldb, 0, c);
  stage_half(SA1, c.Ab, c.brow, c.lda, 1, c);
  stage_half(SB1, c.Bb, c.bcol, c.ldb, 1, c);
  VMCNT4();   // tile0 landed; tile1 in flight
  BARRIER();

  for (int t4 = 0; t4 < NT; t4 += 4) {
    tile_step(SA0, SB0, SA2, SB2, t4 + 0, NT, c, acc);
    tile_step(SA1, SB1, SA3, SB3, t4 + 1, NT, c, acc);
    tile_step(SA2, SB2, SA0, SB0, t4 + 2, NT, c, acc);
    tile_step(SA3, SB3, SA1, SB1, t4 + 3, NT, c, acc);
  }

  // epilogue: C/D layout col = lane&15, row = (lane>>4)*4 + j
#pragma unroll
  for (int m = 0; m < 8; ++m) {
#pragma unroll
    for (int n = 0; n < 4; ++n) {
      const long col = c.bcol + c.wc * 64 + n * 16 + c.l15;
      const float bv = bias ? bias[col] : 0.0f;
#pragma unroll
      for (int j = 0; j < 4; ++j) {
        const long row = c.brow + c.wr * 128 + m * 16 + c.lk * 4 + j;
        const float v = acc[m][n][j] * scale + bv;
        if (OUT_F16)
          ((f16*)Cv)[(long)z * sC + row * ldc + col] = (f16)v;
        else
          ((float*)Cv)[(long)z * sC + row * ldc + col] = v;
      }
    }
  }
}

__global__ void cast_f32_f16(const float* __restrict__ in, f16* __restrict__ out, long n) {
  long i = ((long)blockIdx.x * blockDim.x + threadIdx.x) * 4;
  const long stride = (long)gridDim.x * blockDim.x * 4;
  for (; i < n; i += stride) {
    const float4 v = *reinterpret_cast<const float4*>(in + i);
    f16x4 h;
    h.x = (f16)v.x; h.y = (f16)v.y; h.z = (f16)v.z; h.w = (f16)v.w;
    *reinterpret_cast<f16x4*>(out + i) = h;
  }
}

// vt[b][h][s] = qkv[b*2048+s][4096+h]   (extract V and transpose, per batch)
__global__ __launch_bounds__(256)
void transpose_v(const f16* __restrict__ qkv, f16* __restrict__ vt) {
  __shared__ f16 t[32][33];
  const int b = blockIdx.z;
  const int s0 = blockIdx.y * 32, h0 = blockIdx.x * 32;
  const int tx = threadIdx.x, ty = threadIdx.y;  // 32 x 8
  const f16* src = qkv + (long)b * 2048 * 6144 + 4096;
  f16* dst = vt + (long)b * 2048 * 2048;
#pragma unroll
  for (int i = 0; i < 4; ++i)
    t[ty + i * 8][tx] = src[(long)(s0 + ty + i * 8) * 6144 + h0 + tx];
  __syncthreads();
#pragma unroll
  for (int i = 0; i < 4; ++i)
    dst[(long)(h0 + ty + i * 8) * 2048 + s0 + tx] = t[tx][ty + i * 8];
}

// one block per row of 2048 f32 scores; writes f16 probs in-place (row stride 4096 f16)
__global__ __launch_bounds__(256)
void softmax_rows(float* __restrict__ scores) {
  const long row = blockIdx.x;
  float* s = scores + row * 2048;
  const int tid = threadIdx.x;
  const int lane = tid & 63;
  const int wave = tid >> 6;

  const float4 a = *reinterpret_cast<const float4*>(s + tid * 8);
  const float4 b = *reinterpret_cast<const float4*>(s + tid * 8 + 4);
  float v[8] = {a.x, a.y, a.z, a.w, b.x, b.y, b.z, b.w};

  float mx = v[0];
#pragma unroll
  for (int j = 1; j < 8; ++j) mx = fmaxf(mx, v[j]);
#pragma unroll
  for (int off = 32; off >= 1; off >>= 1) mx = fmaxf(mx, __shfl_xor(mx, off));
  __shared__ float red[4];
  if (lane == 0) red[wave] = mx;
  __syncthreads();
  mx = fmaxf(fmaxf(red[0], red[1]), fmaxf(red[2], red[3]));

  float sum = 0.f;
#pragma unroll
  for (int j = 0; j < 8; ++j) { v[j] = __expf(v[j] - mx); sum += v[j]; }
#pragma unroll
  for (int off = 32; off >= 1; off >>= 1) sum += __shfl_xor(sum, off);
  __shared__ float red2[4];
  if (lane == 0) red2[wave] = sum;
  __syncthreads();
  const float inv = 1.0f / (red2[0] + red2[1] + red2[2] + red2[3]);

  f16* p = reinterpret_cast<f16*>(scores) + row * 4096 + tid * 8;
  f16x8 h;
#pragma unroll
  for (int j = 0; j < 8; ++j) h[j] = (f16)(v[j] * inv);
  *reinterpret_cast<f16x8*>(p) = h;
}

extern "C" void kernel_launch(void* const* d_in, const int* in_sizes, int n_in,
                              void* d_out, int out_size, void* d_ws, size_t ws_size,
                              hipStream_t stream) {
  const float* x     = (const float*)d_in[0];  // [4,2048,2048]
  const float* w_qkv = (const float*)d_in[1];  // [6144,2048]
  const float* b_qkv = (const float*)d_in[2];  // [6144]
  const float* w_out = (const float*)d_in[3];  // [2048,2048]
  const float* b_out = (const float*)d_in[4];  // [2048]
  float* out = (float*)d_out;                  // [4,2048,2048] f32

  char* ws = (char*)d_ws;
  f16*   Xh    = (f16*)(ws + 0);           //  33.5 MB  [8192][2048]
  f16*   Wqkvh = (f16*)(ws + 33554432L);   //  25.2 MB  [6144][2048]
  f16*   Wouth = (f16*)(ws + 58720256L);   //   8.4 MB  [2048][2048]
  f16*   QKV   = (f16*)(ws + 67108864L);   // 100.7 MB  [8192][6144]
  float* SC    = (float*)(ws + 167772160L);//  67.1 MB  [4][2048][2048] f32 (probs f16 in-place)
  f16*   VT    = (f16*)(ws + 234881024L);  //  33.5 MB  [4][2048][2048]
  f16*   CTX   = Xh;                       // reuse X region after gemm1

  const float inv_sqrt_h = 0.022097086912079608f;  // 1/sqrt(2048)

  cast_f32_f16<<<2048, 256, 0, stream>>>(x,     Xh,    16777216L);
  cast_f32_f16<<<2048, 256, 0, stream>>>(w_qkv, Wqkvh, 12582912L);
  cast_f32_f16<<<1024, 256, 0, stream>>>(w_out, Wouth, 4194304L);

  // qkv = x @ w_qkv^T + b_qkv   [8192 x 6144]
  gemm256<1><<<dim3(24, 32, 1), 512, 0, stream>>>(
      Xh, 2048, 0, Wqkvh, 2048, 0, QKV, 6144, 0, b_qkv, 1.0f, 2048);

  // scores = Q @ K^T / sqrt(H)  per batch  [2048 x 2048] f32
  gemm256<0><<<dim3(8, 8, 4), 512, 0, stream>>>(
      QKV, 6144, 2048L * 6144, QKV + 2048, 6144, 2048L * 6144,
      SC, 2048, 2048L * 2048, nullptr, inv_sqrt_h, 2048);

  transpose_v<<<dim3(64, 64, 4), dim3(32, 8), 0, stream>>>(QKV, VT);

  softmax_rows<<<8192, 256, 0, stream>>>(SC);

  // context = P @ V  per batch (probs f16 in-place in SC, row stride 4096)
  gemm256<1><<<dim3(8, 8, 4), 512, 0, stream>>>(
      (const f16*)SC, 4096, 2048L * 4096, VT, 2048, 2048L * 2048,
      CTX, 2048, 2048L * 2048, nullptr, 1.0f, 2048);

  // out = context @ w_out^T + b_out   [8192 x 2048] f32
  gemm256<0><<<dim3(8, 32, 1), 512, 0, stream>>>(
      CTX, 2048, 0, Wouth, 2048, 0, out, 2048, 0, b_out, 1.0f, 2048);
}